// Round 1
// baseline (1237.972 us; speedup 1.0000x reference)
//
#include <hip/hip_runtime.h>
#include <hip/hip_bf16.h>

#define BATCH 4096
#define T_LEN 1024
#define HID 32
#define CT 64
#define NCHUNK (T_LEN / CT)

typedef short bf16x8 __attribute__((ext_vector_type(8)));
typedef float f32x4 __attribute__((ext_vector_type(4)));

// float -> bf16 RNE; also returns the bf16 value re-expanded to f32 (exact)
__device__ __forceinline__ short f32_to_bf16_rne(float f, float* back) {
    unsigned u = __float_as_uint(f);
    unsigned r = (u + 0x7fffu + ((u >> 16) & 1u)) & 0xffff0000u;
    *back = __uint_as_float(r);
    return (short)(r >> 16);
}

// One wave (64 threads) advances 16 batch rows through all 1024 timesteps.
// Lane l: batch = b0 + (l&15); rg = l>>4 selects the hidden-slot group.
// Hidden-axis permutation: slot i of rg holds logical j = 16*(i>>2)+4*rg+(i&3).
// This makes MFMA C-output quads land exactly in the lane's next B-fragment.
__global__ void __launch_bounds__(64, 1)
gru_fused(const float* __restrict__ xg, const float* __restrict__ h0g,
          const float* __restrict__ Wih, const float* __restrict__ Whh,
          const float* __restrict__ bih, const float* __restrict__ bhh,
          const float* __restrict__ Wout, const float* __restrict__ boutp,
          float* __restrict__ outp)
{
    const int l  = threadIdx.x;
    const int rg = l >> 4;
    const int cl = l & 15;
    const int b0 = blockIdx.x << 4;

    __shared__ float xbuf[16][68];   // stride 68: conflict-free + 16B-aligned rows
    __shared__ float obuf[16][68];

    // ---- per-lane weight fragments: W_hh split hi/lo bf16, 6 M-tiles of 16 gates ----
    bf16x8 WAhi[6], WAlo[6];
#pragma unroll
    for (int m = 0; m < 6; ++m) {
#pragma unroll
        for (int i = 0; i < 8; ++i) {
            int j = 16 * (i >> 2) + 4 * rg + (i & 3);   // permuted hidden column
            float w = Whh[(m * 16 + cl) * HID + j];     // A row = lane&15 within tile
            float hif, dum;
            WAhi[m][i] = f32_to_bf16_rne(w, &hif);
            WAlo[m][i] = f32_to_bf16_rne(w - hif, &dum);
        }
    }
    // per-lane gate constants for the C layout (row = 4*rg + r within tile m)
    float wih[24], bias[24];
#pragma unroll
    for (int m = 0; m < 6; ++m)
#pragma unroll
        for (int r = 0; r < 4; ++r) {
            int g = m * 16 + 4 * rg + r;
            wih[m * 4 + r]  = Wih[g];
            bias[m * 4 + r] = (m < 4) ? (bih[g] + bhh[g]) : bhh[g]; // n-gates: b_hh only
        }
    float bihn[8];
#pragma unroll
    for (int i = 0; i < 8; ++i)
        bihn[i] = bih[64 + 16 * (i >> 2) + 4 * rg + (i & 3)];
    float wout[8];
#pragma unroll
    for (int i = 0; i < 8; ++i)
        wout[i] = Wout[16 * (i >> 2) + 4 * rg + (i & 3)];
    const float bout = boutp[0];

    // ---- h0 ----
    float h[8];
    bf16x8 Bhi, Blo;
#pragma unroll
    for (int i = 0; i < 8; ++i) {
        int j = 16 * (i >> 2) + 4 * rg + (i & 3);
        float hv = h0g[(size_t)(b0 + cl) * HID + j];
        h[i] = hv;
        float hf, d;
        Bhi[i] = f32_to_bf16_rne(hv, &hf);
        Blo[i] = f32_to_bf16_rne(hv - hf, &d);
    }

    for (int tc = 0; tc < NCHUNK; ++tc) {
        __syncthreads();   // xbuf/obuf cross-lane reuse fence
#pragma unroll
        for (int q = 0; q < 16; ++q)
            xbuf[q][l] = xg[(size_t)(b0 + q) * T_LEN + tc * CT + l]; // coalesced
        __syncthreads();

        for (int tt = 0; tt < CT; ++tt) {
            float xv = xbuf[cl][tt];   // broadcast across the 4 rg groups

            f32x4 acc[6];
#pragma unroll
            for (int m = 0; m < 6; ++m)
#pragma unroll
                for (int r = 0; r < 4; ++r)
                    acc[m][r] = (m < 4) ? fmaf(xv, wih[m * 4 + r], bias[m * 4 + r])
                                        : bias[m * 4 + r];
            // gh = W_hh · h  (3-term bf16 decomposition, fp32 accumulate)
#pragma unroll
            for (int m = 0; m < 6; ++m) {
                acc[m] = __builtin_amdgcn_mfma_f32_16x16x32_bf16(WAhi[m], Bhi, acc[m], 0, 0, 0);
                acc[m] = __builtin_amdgcn_mfma_f32_16x16x32_bf16(WAhi[m], Blo, acc[m], 0, 0, 0);
                acc[m] = __builtin_amdgcn_mfma_f32_16x16x32_bf16(WAlo[m], Bhi, acc[m], 0, 0, 0);
            }

            float op = 0.f;
#pragma unroll
            for (int tp = 0; tp < 2; ++tp)
#pragma unroll
                for (int r = 0; r < 4; ++r) {
                    int i = tp * 4 + r;
                    float rpre = acc[tp][r];          // r-gate pre-act (has x + biases)
                    float zpre = acc[2 + tp][r];      // z-gate pre-act
                    float hn   = acc[4 + tp][r];      // W_hn·h + b_hn only
                    float rr = 1.f / (1.f + __expf(-rpre));
                    float zz = 1.f / (1.f + __expf(-zpre));
                    float npre = fmaf(xv, wih[(4 + tp) * 4 + r], bihn[i]) + rr * hn;
                    float e2 = __expf(2.f * npre);
                    float nn = 1.f - 2.f / (1.f + e2);     // tanh
                    float hv = nn + zz * (h[i] - nn);       // (1-z)n + z h
                    h[i] = hv;
                    op = fmaf(hv, wout[i], op);
                    float hf, d;
                    Bhi[i] = f32_to_bf16_rne(hv, &hf);      // next-step B fragment
                    Blo[i] = f32_to_bf16_rne(hv - hf, &d);
                }
            // reduce output projection across the 4 rg groups
            op += __shfl_xor(op, 16, 64);
            op += __shfl_xor(op, 32, 64);
            if (rg == 0) obuf[cl][tt] = op + bout;
        }
        __syncthreads();
        // coalesced flush of 16 rows x 64 t
        {
            int row = l >> 2;
            int seg = l & 3;
#pragma unroll
            for (int q = 0; q < 4; ++q) {
                int t0 = seg * 16 + q * 4;
                f32x4 v = *reinterpret_cast<const f32x4*>(&obuf[row][t0]);
                *reinterpret_cast<f32x4*>(
                    &outp[(size_t)(b0 + row) * T_LEN + tc * CT + t0]) = v;
            }
        }
    }

    // h_last at d_out[B*T + b*32 + j]
#pragma unroll
    for (int i = 0; i < 8; ++i) {
        int j = 16 * (i >> 2) + 4 * rg + (i & 3);
        outp[(size_t)BATCH * T_LEN + (size_t)(b0 + cl) * HID + j] = h[i];
    }
}

extern "C" void kernel_launch(void* const* d_in, const int* in_sizes, int n_in,
                              void* d_out, int out_size, void* d_ws, size_t ws_size,
                              hipStream_t stream) {
    const float* x     = (const float*)d_in[0];
    const float* h0    = (const float*)d_in[1];
    const float* Wih   = (const float*)d_in[2];
    const float* Whh   = (const float*)d_in[3];
    const float* bihv  = (const float*)d_in[4];
    const float* bhhv  = (const float*)d_in[5];
    const float* Woutv = (const float*)d_in[6];
    const float* boutv = (const float*)d_in[7];
    float* out = (float*)d_out;

    gru_fused<<<dim3(BATCH / 16), dim3(64), 0, stream>>>(
        x, h0, Wih, Whh, bihv, bhhv, Woutv, boutv, out);
}

// Round 3
// 534.121 us; speedup vs baseline: 2.3178x; 2.3178x over previous
//
#include <hip/hip_runtime.h>
#include <hip/hip_bf16.h>

#define BATCH 4096
#define T_LEN 1024
#define HID 32
#define CT 64
#define NCHUNK (T_LEN / CT)

typedef short bf16x8 __attribute__((ext_vector_type(8)));
typedef float f32x4 __attribute__((ext_vector_type(4)));

// float -> bf16 RNE; also returns the bf16 value re-expanded to f32 (exact)
__device__ __forceinline__ short f32_to_bf16_rne(float f, float* back) {
    unsigned u = __float_as_uint(f);
    unsigned r = (u + 0x7fffu + ((u >> 16) & 1u)) & 0xffff0000u;
    *back = __uint_as_float(r);
    return (short)(r >> 16);
}

__device__ __forceinline__ float fast_rcp(float x) { return __builtin_amdgcn_rcpf(x); }

// 2-wave gate split: block = 16 batch rows, 2 waves.
// Wave w computes gate tiles m = {w, 2+w, 4+w}  (r, z, n for hidden half w)
// and owns h_j for j = 16*w + 4*rg + r  (4 per lane, B-fragment slots w*4+r).
// Halves exchanged via LDS each step (parity double-buffer, 1 barrier/step).
// Hidden-axis permutation j = 16*(i>>2)+4*rg+(i&3) makes MFMA C-output quads
// land exactly in the lane's next-step B-fragment slots (verified round 0).
__global__ void __launch_bounds__(128, 1)
gru_fused2(const float* __restrict__ xg, const float* __restrict__ h0g,
           const float* __restrict__ Wih, const float* __restrict__ Whh,
           const float* __restrict__ bih, const float* __restrict__ bhh,
           const float* __restrict__ Wout, const float* __restrict__ boutp,
           float* __restrict__ outp)
{
    const int tid = threadIdx.x;
    const int w  = tid >> 6;          // wave id = hidden half
    const int l  = tid & 63;
    const int rg = (l >> 4) & 3;
    const int cl = l & 15;
    const int b0 = blockIdx.x << 4;

    __shared__ float xbuf[16][68];
    __shared__ float po[8][16][65];               // out-proj partials [w*4+rg][cl][tt]
    __shared__ __align__(16) short exch[2][2][64 * 8];  // [parity][wave][lane*8]

    // ---- weight fragments for this wave's 3 tiles (hi/lo bf16 split) ----
    bf16x8 WAhi[3], WAlo[3];
#pragma unroll
    for (int q = 0; q < 3; ++q) {
        int m = 2 * q + w;
#pragma unroll
        for (int i = 0; i < 8; ++i) {
            int j = 16 * (i >> 2) + 4 * rg + (i & 3);
            float wv = Whh[(m * 16 + cl) * HID + j];
            float hf, d;
            WAhi[q][i] = f32_to_bf16_rne(wv, &hf);
            WAlo[q][i] = f32_to_bf16_rne(wv - hf, &d);
        }
    }
    float wihv[12], biasv[12], bihn[4], wout[4];
#pragma unroll
    for (int q = 0; q < 3; ++q)
#pragma unroll
        for (int r = 0; r < 4; ++r) {
            int g = (2 * q + w) * 16 + 4 * rg + r;
            wihv[q * 4 + r]  = Wih[g];
            biasv[q * 4 + r] = (q < 2) ? (bih[g] + bhh[g]) : bhh[g]; // n: b_hh only
            if (q == 2) bihn[r] = bih[g];
        }
#pragma unroll
    for (int r = 0; r < 4; ++r) wout[r] = Wout[16 * w + 4 * rg + r];
    const float bout = boutp[0];

    // ---- h0: full B fragment + own fp32 h ----
    float h[4];
    bf16x8 Bhi, Blo;
#pragma unroll
    for (int i = 0; i < 8; ++i) {
        int j = 16 * (i >> 2) + 4 * rg + (i & 3);
        float hv = h0g[(size_t)(b0 + cl) * HID + j];
        float hf, d;
        Bhi[i] = f32_to_bf16_rne(hv, &hf);
        Blo[i] = f32_to_bf16_rne(hv - hf, &d);
    }
#pragma unroll
    for (int r = 0; r < 4; ++r)
        h[r] = h0g[(size_t)(b0 + cl) * HID + 16 * w + 4 * rg + r];

    int par = 0;
    for (int tc = 0; tc < NCHUNK; ++tc) {
        // flush previous chunk's output partials (ordered by last step barrier)
        if (tc > 0) {
            int row = tid >> 3, t0 = (tid & 7) * 8;
            float s[8];
#pragma unroll
            for (int u = 0; u < 8; ++u) s[u] = bout;
#pragma unroll
            for (int g = 0; g < 8; ++g)
#pragma unroll
                for (int u = 0; u < 8; ++u) s[u] += po[g][row][t0 + u];
            float* dst = &outp[(size_t)(b0 + row) * T_LEN + (tc - 1) * CT + t0];
            *reinterpret_cast<f32x4*>(dst)     = *reinterpret_cast<f32x4*>(&s[0]);
            *reinterpret_cast<f32x4*>(dst + 4) = *reinterpret_cast<f32x4*>(&s[4]);
        }
        // stage x chunk (each wave 8 rows, coalesced 64-wide)
#pragma unroll
        for (int q = 0; q < 8; ++q)
            xbuf[w * 8 + q][l] = xg[(size_t)(b0 + w * 8 + q) * T_LEN + tc * CT + l];
        __syncthreads();
        float xv = xbuf[cl][0];

        for (int tt = 0; tt < CT; ++tt) {
            float xvn = xbuf[cl][(tt + 1) & 63];   // prefetch next step's x

            f32x4 acc0, acc1, acc2;
#pragma unroll
            for (int r = 0; r < 4; ++r) {
                acc0[r] = fmaf(xv, wihv[r],     biasv[r]);       // r-gate pre
                acc1[r] = fmaf(xv, wihv[4 + r], biasv[4 + r]);   // z-gate pre
                acc2[r] = biasv[8 + r];                           // hn (b_hh only)
            }
            // gh = W_hh · h, 3-term bf16 decomposition, tiles pipelined
            acc0 = __builtin_amdgcn_mfma_f32_16x16x32_bf16(WAhi[0], Bhi, acc0, 0, 0, 0);
            acc1 = __builtin_amdgcn_mfma_f32_16x16x32_bf16(WAhi[1], Bhi, acc1, 0, 0, 0);
            acc2 = __builtin_amdgcn_mfma_f32_16x16x32_bf16(WAhi[2], Bhi, acc2, 0, 0, 0);
            acc0 = __builtin_amdgcn_mfma_f32_16x16x32_bf16(WAhi[0], Blo, acc0, 0, 0, 0);
            acc1 = __builtin_amdgcn_mfma_f32_16x16x32_bf16(WAhi[1], Blo, acc1, 0, 0, 0);
            acc2 = __builtin_amdgcn_mfma_f32_16x16x32_bf16(WAhi[2], Blo, acc2, 0, 0, 0);
            acc0 = __builtin_amdgcn_mfma_f32_16x16x32_bf16(WAlo[0], Bhi, acc0, 0, 0, 0);
            acc1 = __builtin_amdgcn_mfma_f32_16x16x32_bf16(WAlo[1], Bhi, acc1, 0, 0, 0);
            acc2 = __builtin_amdgcn_mfma_f32_16x16x32_bf16(WAlo[2], Bhi, acc2, 0, 0, 0);

            bf16x8 pk;
            float opart = 0.f;
#pragma unroll
            for (int r = 0; r < 4; ++r) {
                float rr   = fast_rcp(1.f + __expf(-acc0[r]));
                float zz   = fast_rcp(1.f + __expf(-acc1[r]));
                float npre = fmaf(rr, acc2[r], fmaf(xv, wihv[8 + r], bihn[r]));
                float nn   = 1.f - 2.f * fast_rcp(1.f + __expf(2.f * npre)); // tanh
                float hv   = nn + zz * (h[r] - nn);
                h[r] = hv;
                opart = fmaf(hv, wout[r], opart);
                float hf, d;
                pk[r]     = f32_to_bf16_rne(hv, &hf);
                pk[4 + r] = f32_to_bf16_rne(hv - hf, &d);
            }
            // exchange own half; partial out-proj off the critical path
            *reinterpret_cast<bf16x8*>(&exch[par][w][l * 8]) = pk;
            po[w * 4 + rg][cl][tt] = opart;
            __syncthreads();
            bf16x8 oth = *reinterpret_cast<const bf16x8*>(&exch[par][1 - w][l * 8]);
            if (w == 0) {
#pragma unroll
                for (int r = 0; r < 4; ++r) {
                    Bhi[r]     = pk[r];      Blo[r]     = pk[4 + r];
                    Bhi[4 + r] = oth[r];     Blo[4 + r] = oth[4 + r];
                }
            } else {
#pragma unroll
                for (int r = 0; r < 4; ++r) {
                    Bhi[4 + r] = pk[r];      Blo[4 + r] = pk[4 + r];
                    Bhi[r]     = oth[r];     Blo[r]     = oth[4 + r];
                }
            }
            par ^= 1;
            xv = xvn;
        }
    }

    // final chunk flush
    {
        int row = tid >> 3, t0 = (tid & 7) * 8;
        float s[8];
#pragma unroll
        for (int u = 0; u < 8; ++u) s[u] = bout;
#pragma unroll
        for (int g = 0; g < 8; ++g)
#pragma unroll
            for (int u = 0; u < 8; ++u) s[u] += po[g][row][t0 + u];
        float* dst = &outp[(size_t)(b0 + row) * T_LEN + (NCHUNK - 1) * CT + t0];
        *reinterpret_cast<f32x4*>(dst)     = *reinterpret_cast<f32x4*>(&s[0]);
        *reinterpret_cast<f32x4*>(dst + 4) = *reinterpret_cast<f32x4*>(&s[4]);
    }

    // h_last at d_out[B*T + b*32 + j] (own half)
#pragma unroll
    for (int r = 0; r < 4; ++r)
        outp[(size_t)BATCH * T_LEN + (size_t)(b0 + cl) * HID + 16 * w + 4 * rg + r] = h[r];
}

extern "C" void kernel_launch(void* const* d_in, const int* in_sizes, int n_in,
                              void* d_out, int out_size, void* d_ws, size_t ws_size,
                              hipStream_t stream) {
    const float* x     = (const float*)d_in[0];
    const float* h0    = (const float*)d_in[1];
    const float* Wih   = (const float*)d_in[2];
    const float* Whh   = (const float*)d_in[3];
    const float* bihv  = (const float*)d_in[4];
    const float* bhhv  = (const float*)d_in[5];
    const float* Woutv = (const float*)d_in[6];
    const float* boutv = (const float*)d_in[7];
    float* out = (float*)d_out;

    gru_fused2<<<dim3(BATCH / 16), dim3(128), 0, stream>>>(
        x, h0, Wih, Whh, bihv, bhhv, Woutv, boutv, out);
}

// Round 6
// 460.068 us; speedup vs baseline: 2.6908x; 1.1610x over previous
//
#include <hip/hip_runtime.h>
#include <hip/hip_bf16.h>

#define BATCH 4096
#define T_LEN 1024
#define HID 32
#define CT 64
#define NCHUNK (T_LEN / CT)
#define L2E 1.4426950408889634f

typedef short bf16x8 __attribute__((ext_vector_type(8)));
typedef float f32x4 __attribute__((ext_vector_type(4)));

// float -> bf16 RNE; also returns the bf16 value re-expanded to f32 (exact)
__device__ __forceinline__ short bf16hi_rne(float f, float* back) {
    unsigned u = __float_as_uint(f);
    unsigned r = (u + 0x7fffu + ((u >> 16) & 1u)) & 0xffff0000u;
    *back = __uint_as_float(r);
    return (short)(r >> 16);
}
__device__ __forceinline__ float fast_rcp(float x)  { return __builtin_amdgcn_rcpf(x); }
__device__ __forceinline__ float fast_exp2(float x) { return __builtin_amdgcn_exp2f(x); }

// 2-wave gate split, per-wave slot permutation, exp2-prescaled weights.
// Wave w computes gate tiles m = {w, 2+w, 4+w} (r,z,n for hidden half w) and
// owns h_j, j = 16w + 4rg + r. Per-wave slot->hidden map
// j(i) = 16*((i>>2)^w) + 4rg + (i&3): own half is ALWAYS slots 0..3, so the
// MFMA C-output quad feeds Bhi/Blo[0..3] directly; other half arrives via one
// b128 LDS read (parity double-buffer, parity = step&1, compile-time in the
// unrolled quad). r/z rows prescaled by log2(e), n rows by 2*log2(e) so
// sigmoid = rcp(1+exp2(-pre)), tanh = 1 - 2*rcp(1+exp2(pre)).
__global__ void __launch_bounds__(128, 1)
gru_fused3(const float* __restrict__ xg, const float* __restrict__ h0g,
           const float* __restrict__ Wih, const float* __restrict__ Whh,
           const float* __restrict__ bih, const float* __restrict__ bhh,
           const float* __restrict__ Wout, const float* __restrict__ boutp,
           float* __restrict__ outp)
{
    const int tid = threadIdx.x;
    const int w   = tid >> 6;
    const int l   = tid & 63;
    const int rg  = (l >> 4) & 3;
    const int cl  = l & 15;
    const int b0  = blockIdx.x << 4;

    __shared__ float xbuf[16][68];
    __shared__ float po[8][16][68];                      // out-proj partials
    __shared__ __align__(16) short exch[2][2][64 * 8];   // [parity][wave][lane*8]

    // ---- A fragments (prescaled, hi/lo bf16 split), per-wave slot map ----
    bf16x8 WAhi[3], WAlo[3];
#pragma unroll
    for (int q = 0; q < 3; ++q) {
        const int m = 2 * q + w;
        const float sc = (q < 2) ? L2E : 2.0f * L2E;
#pragma unroll
        for (int i = 0; i < 8; ++i) {
            int j = 16 * ((i >> 2) ^ w) + 4 * rg + (i & 3);
            float wv = Whh[(m * 16 + cl) * HID + j] * sc;
            float hf, d;
            WAhi[q][i] = bf16hi_rne(wv, &hf);
            WAlo[q][i] = bf16hi_rne(wv - hf, &d);
        }
    }
    float wrz[8], brz[8], win[4], bin[4], wout4[4];
    f32x4 biasN;
#pragma unroll
    for (int q = 0; q < 2; ++q)
#pragma unroll
        for (int r = 0; r < 4; ++r) {
            int g = (2 * q + w) * 16 + 4 * rg + r;
            wrz[q * 4 + r] = L2E * Wih[g];
            brz[q * 4 + r] = L2E * (bih[g] + bhh[g]);
        }
#pragma unroll
    for (int r = 0; r < 4; ++r) {
        int g = (4 + w) * 16 + 4 * rg + r;
        win[r]   = 2.0f * L2E * Wih[g];
        bin[r]   = 2.0f * L2E * bih[g];
        biasN[r] = 2.0f * L2E * bhh[g];
        wout4[r] = Wout[16 * w + 4 * rg + r];
    }
    const float bout = boutp[0];

    // ---- h0 ----
    float h[4];
    bf16x8 Bhi, Blo;
#pragma unroll
    for (int i = 0; i < 8; ++i) {
        int j = 16 * ((i >> 2) ^ w) + 4 * rg + (i & 3);
        float hv = h0g[(size_t)(b0 + cl) * HID + j];
        float hf, d;
        Bhi[i] = bf16hi_rne(hv, &hf);
        Blo[i] = bf16hi_rne(hv - hf, &d);
    }
#pragma unroll
    for (int r = 0; r < 4; ++r)
        h[r] = h0g[(size_t)(b0 + cl) * HID + 16 * w + 4 * rg + r];

    short* const exMy       = &exch[0][w][l * 8];       // + (step&1)*1024 shorts
    const short* const exOt = &exch[0][1 - w][l * 8];

    for (int tc = 0; tc < NCHUNK; ++tc) {
        if (tc > 0) {  // flush previous chunk's output (po writes barrier-ordered)
            int row = tid >> 3, t0 = (tid & 7) * 8;
            f32x4 s0 = {bout, bout, bout, bout}, s1 = s0;
#pragma unroll
            for (int g = 0; g < 8; ++g) {
                s0 += *reinterpret_cast<const f32x4*>(&po[g][row][t0]);
                s1 += *reinterpret_cast<const f32x4*>(&po[g][row][t0 + 4]);
            }
            float* dst = &outp[(size_t)(b0 + row) * T_LEN + (tc - 1) * CT + t0];
            *reinterpret_cast<f32x4*>(dst)     = s0;
            *reinterpret_cast<f32x4*>(dst + 4) = s1;
        }
#pragma unroll
        for (int q = 0; q < 8; ++q)
            xbuf[w * 8 + q][l] = xg[(size_t)(b0 + w * 8 + q) * T_LEN + tc * CT + l];
        __syncthreads();
        f32x4 xq = *reinterpret_cast<const f32x4*>(&xbuf[cl][0]);

        for (int qt = 0; qt < 16; ++qt) {
            // prefetch next quad (qt==15 reads stale quad 0 -> discarded at restage)
            f32x4 xqn = *reinterpret_cast<const f32x4*>(&xbuf[cl][((qt + 1) & 15) * 4]);
            f32x4 opv;
#pragma unroll
            for (int s = 0; s < 4; ++s) {
                const float xv = xq[s];
                f32x4 i0, i1;
#pragma unroll
                for (int r = 0; r < 4; ++r) {
                    i0[r] = fmaf(xv, wrz[r],     brz[r]);
                    i1[r] = fmaf(xv, wrz[4 + r], brz[4 + r]);
                }
                f32x4 a0 = __builtin_amdgcn_mfma_f32_16x16x32_bf16(WAhi[0], Bhi, i0,    0, 0, 0);
                f32x4 a1 = __builtin_amdgcn_mfma_f32_16x16x32_bf16(WAhi[1], Bhi, i1,    0, 0, 0);
                f32x4 a2 = __builtin_amdgcn_mfma_f32_16x16x32_bf16(WAhi[2], Bhi, biasN, 0, 0, 0);
                a0 = __builtin_amdgcn_mfma_f32_16x16x32_bf16(WAhi[0], Blo, a0, 0, 0, 0);
                a1 = __builtin_amdgcn_mfma_f32_16x16x32_bf16(WAhi[1], Blo, a1, 0, 0, 0);
                a2 = __builtin_amdgcn_mfma_f32_16x16x32_bf16(WAhi[2], Blo, a2, 0, 0, 0);
                a0 = __builtin_amdgcn_mfma_f32_16x16x32_bf16(WAlo[0], Bhi, a0, 0, 0, 0);
                a1 = __builtin_amdgcn_mfma_f32_16x16x32_bf16(WAlo[1], Bhi, a1, 0, 0, 0);
                a2 = __builtin_amdgcn_mfma_f32_16x16x32_bf16(WAlo[2], Bhi, a2, 0, 0, 0);

                bf16x8 pk;
                float op = 0.f;
#pragma unroll
                for (int r = 0; r < 4; ++r) {
                    float rr = fast_rcp(1.f + fast_exp2(-a0[r]));
                    float zz = fast_rcp(1.f + fast_exp2(-a1[r]));
                    float np = fmaf(rr, a2[r], fmaf(xv, win[r], bin[r]));
                    float nn = fmaf(-2.f, fast_rcp(1.f + fast_exp2(np)), 1.f);
                    float hv = fmaf(zz, h[r] - nn, nn);
                    h[r] = hv;
                    op = fmaf(hv, wout4[r], op);
                    float hf;
                    pk[r]     = bf16hi_rne(hv, &hf);
                    pk[4 + r] = (short)(__float_as_uint(hv - hf) >> 16); // trunc lo
                }
                opv[s] = op;
                *reinterpret_cast<bf16x8*>(exMy + (s & 1) * 1024) = pk;
                if (s == 3)  // po write must precede this step's barrier
                    *reinterpret_cast<f32x4*>(&po[w * 4 + rg][cl][qt * 4]) = opv;
                __syncthreads();
                bf16x8 oth = *reinterpret_cast<const bf16x8*>(exOt + (s & 1) * 1024);
#pragma unroll
                for (int r = 0; r < 4; ++r) {
                    Bhi[r]     = pk[r];      Blo[r]     = pk[4 + r];   // own half
                    Bhi[4 + r] = oth[r];     Blo[4 + r] = oth[4 + r];  // other half
                }
            }
            xq = xqn;
        }
    }

    // final chunk flush
    {
        int row = tid >> 3, t0 = (tid & 7) * 8;
        f32x4 s0 = {bout, bout, bout, bout}, s1 = s0;
#pragma unroll
        for (int g = 0; g < 8; ++g) {
            s0 += *reinterpret_cast<const f32x4*>(&po[g][row][t0]);
            s1 += *reinterpret_cast<const f32x4*>(&po[g][row][t0 + 4]);
        }
        float* dst = &outp[(size_t)(b0 + row) * T_LEN + (NCHUNK - 1) * CT + t0];
        *reinterpret_cast<f32x4*>(dst)     = s0;
        *reinterpret_cast<f32x4*>(dst + 4) = s1;
    }

    // h_last at d_out[B*T + b*32 + j] (own half)
#pragma unroll
    for (int r = 0; r < 4; ++r)
        outp[(size_t)BATCH * T_LEN + (size_t)(b0 + cl) * HID + 16 * w + 4 * rg + r] = h[r];
}

extern "C" void kernel_launch(void* const* d_in, const int* in_sizes, int n_in,
                              void* d_out, int out_size, void* d_ws, size_t ws_size,
                              hipStream_t stream) {
    const float* x     = (const float*)d_in[0];
    const float* h0    = (const float*)d_in[1];
    const float* Wih   = (const float*)d_in[2];
    const float* Whh   = (const float*)d_in[3];
    const float* bihv  = (const float*)d_in[4];
    const float* bhhv  = (const float*)d_in[5];
    const float* Woutv = (const float*)d_in[6];
    const float* boutv = (const float*)d_in[7];
    float* out = (float*)d_out;

    gru_fused3<<<dim3(BATCH / 16), dim3(128), 0, stream>>>(
        x, h0, Wih, Whh, bihv, bhhv, Woutv, boutv, out);
}